// Round 1
// baseline (274.837 us; speedup 1.0000x reference)
//
#include <hip/hip_runtime.h>
#include <hip/hip_bf16.h>
#include <cstdint>

// Problem constants
#define BATCH 8
#define SEQ   1024          // LQ == LK
#define DMODEL 1024
#define NHEAD 8
#define DHEAD 128
#define MROWS (BATCH * SEQ) // 8192

using short8 = __attribute__((ext_vector_type(8))) short;
using f32x4  = __attribute__((ext_vector_type(4))) float;
typedef unsigned short u16;

__device__ inline u16 f2bf(float f) {
    union { float f; uint32_t u; } v; v.f = f;
    uint32_t r = (v.u + 0x7FFFu + ((v.u >> 16) & 1u)) >> 16;
    return (u16)r;
}

// ---------------------------------------------------------------------------
// Kernel 1: transpose+convert fp32 [1024x1024] -> bf16 [1024x1024]^T
// z=0: Wq -> WqT ; z=1: Wk -> WkT ; z>=2: k[b] -> Vt[b]  (Vt[b][d][key])
// ---------------------------------------------------------------------------
__global__ void transpose_conv(const float* __restrict__ Wq,
                               const float* __restrict__ Wk,
                               const float* __restrict__ kin,
                               u16* __restrict__ WqT,
                               u16* __restrict__ WkT,
                               u16* __restrict__ Vt) {
    __shared__ float tile[32][33];
    int z = blockIdx.z;
    const float* src;
    u16* dst;
    if (z == 0)      { src = Wq; dst = WqT; }
    else if (z == 1) { src = Wk; dst = WkT; }
    else {
        src = kin + (size_t)(z - 2) * DMODEL * SEQ;
        dst = Vt  + (size_t)(z - 2) * DMODEL * SEQ;
    }
    int x  = blockIdx.x * 32 + threadIdx.x;
    int y0 = blockIdx.y * 32;
    for (int i = threadIdx.y; i < 32; i += 8)
        tile[i][threadIdx.x] = src[(size_t)(y0 + i) * 1024 + x];
    __syncthreads();
    int xo  = y0 + threadIdx.x;
    int yo0 = blockIdx.x * 32;
    for (int i = threadIdx.y; i < 32; i += 8)
        dst[(size_t)(yo0 + i) * 1024 + xo] = f2bf(tile[threadIdx.x][i]);
}

// ---------------------------------------------------------------------------
// Kernel 2: GEMM  Out[m][n] = (A[m][:] . BT[n][:] + bias[n]) * scale  -> bf16
// A fp32 [8192x1024], BT bf16 [1024(n) x 1024(k)], Out bf16 [8192x1024]
// 128x128 tile, BK=32, 256 threads (4 waves, 2x2), mfma 16x16x32 bf16
// ---------------------------------------------------------------------------
#define LDA 40   // padded leading dim (ushorts) for 128x32 LDS tiles
__global__ __launch_bounds__(256) void gemm_bias(const float* __restrict__ A,
                                                 const u16* __restrict__ BT,
                                                 const float* __restrict__ bias,
                                                 u16* __restrict__ Out,
                                                 float scale) {
    __shared__ __align__(16) u16 As[128 * LDA];
    __shared__ __align__(16) u16 Bs[128 * LDA];
    int m0 = blockIdx.y * 128;
    int n0 = blockIdx.x * 128;
    int t = threadIdx.x;
    int lane = t & 63, w = t >> 6;
    int wm = w >> 1, wn = w & 1;
    int lr = lane & 15, lg = lane >> 4;

    f32x4 acc[4][4] = {};

    for (int k0 = 0; k0 < DMODEL; k0 += 32) {
        // stage A tile 128x32 (fp32 -> bf16)
        {
            int row = t >> 3;          // 0..31
            int c4  = (t & 7) * 4;     // 0..28
            for (int i = 0; i < 4; ++i) {
                const float4 v = *(const float4*)&A[(size_t)(m0 + row + i * 32) * 1024 + k0 + c4];
                uint2 pk;
                pk.x = (uint32_t)f2bf(v.x) | ((uint32_t)f2bf(v.y) << 16);
                pk.y = (uint32_t)f2bf(v.z) | ((uint32_t)f2bf(v.w) << 16);
                *(uint2*)&As[(row + i * 32) * LDA + c4] = pk;
            }
        }
        // stage B tile 128x32 (bf16 passthrough)
        {
            int row = t >> 2;          // 0..63
            int c8  = (t & 3) * 8;     // 0..24
            for (int i = 0; i < 2; ++i) {
                uint4 v = *(const uint4*)&BT[(size_t)(n0 + row + i * 64) * 1024 + k0 + c8];
                *(uint4*)&Bs[(row + i * 64) * LDA + c8] = v;
            }
        }
        __syncthreads();
        short8 af[4], bf[4];
        for (int fm = 0; fm < 4; ++fm)
            af[fm] = *(const short8*)&As[(wm * 64 + fm * 16 + lr) * LDA + lg * 8];
        for (int fn = 0; fn < 4; ++fn)
            bf[fn] = *(const short8*)&Bs[(wn * 64 + fn * 16 + lr) * LDA + lg * 8];
        for (int fm = 0; fm < 4; ++fm)
            for (int fn = 0; fn < 4; ++fn)
                acc[fm][fn] = __builtin_amdgcn_mfma_f32_16x16x32_bf16(af[fm], bf[fn], acc[fm][fn], 0, 0, 0);
        __syncthreads();
    }
    // epilogue: add bias, scale, store bf16
    for (int fm = 0; fm < 4; ++fm)
        for (int fn = 0; fn < 4; ++fn)
            for (int j = 0; j < 4; ++j) {
                int row = m0 + wm * 64 + fm * 16 + lg * 4 + j;
                int col = n0 + wn * 64 + fn * 16 + lr;
                float v = (acc[fm][fn][j] + bias[col]) * scale;
                Out[(size_t)row * 1024 + col] = f2bf(v);
            }
}

// ---------------------------------------------------------------------------
// Kernel 3: flash attention.  Per block: one (b,h), 64 q-rows (wave: 16 rows).
// Writes pre-residual attention output (fp32) into d_out.
// ---------------------------------------------------------------------------
#define LDK 136  // 64 x 128 K tile, padded
#define LDV 72   // 128 x 64 V^T tile, padded
#define LDP 72   // 16 x 64 P tile per wave, padded
__global__ __launch_bounds__(256) void attn_kernel(const u16* __restrict__ Qb,
                                                   const u16* __restrict__ Kb,
                                                   const u16* __restrict__ Vt,
                                                   float* __restrict__ AO) {
    __shared__ __align__(16) u16 Ks[64 * LDK];
    __shared__ __align__(16) u16 Vts[128 * LDV];
    __shared__ __align__(16) u16 Pl[4][16 * LDP];

    int bh = blockIdx.y;
    int b = bh >> 3, h = bh & 7;
    int q0 = blockIdx.x * 64;
    int t = threadIdx.x, lane = t & 63, w = t >> 6;
    int lr = lane & 15, lg = lane >> 4;

    // Q fragments for this wave's 16 rows (already scaled by 1/sqrt(DH))
    short8 qf[4];
    {
        size_t qbase = (size_t)(b * SEQ + q0 + w * 16 + lr) * 1024 + h * DHEAD;
        for (int kk = 0; kk < 4; ++kk)
            qf[kk] = *(const short8*)&Qb[qbase + kk * 32 + lg * 8];
    }

    float m_i[4], l_i[4];
    f32x4 o[8] = {};
    for (int j = 0; j < 4; ++j) { m_i[j] = -1e30f; l_i[j] = 0.f; }

    for (int k0 = 0; k0 < SEQ; k0 += 64) {
        __syncthreads();
        // stage K tile: 64 keys x 128 d
        {
            int off = t * 8;
            for (int i = 0; i < 4; ++i) {
                int e = off + i * 2048;
                int row = e >> 7, col = e & 127;
                *(uint4*)&Ks[row * LDK + col] =
                    *(const uint4*)&Kb[(size_t)(b * SEQ + k0 + row) * 1024 + h * DHEAD + col];
            }
            // stage V^T tile: 128 d x 64 keys
            for (int i = 0; i < 4; ++i) {
                int e = off + i * 2048;
                int d = e >> 6, col = e & 63;
                *(uint4*)&Vts[d * LDV + col] =
                    *(const uint4*)&Vt[(size_t)((b * NHEAD + h) * DHEAD + d) * 1024 + k0 + col];
            }
        }
        __syncthreads();

        // S = Q K^T  (16 rows x 64 keys per wave)
        f32x4 s[4] = {};
        for (int fn = 0; fn < 4; ++fn)
            for (int kk = 0; kk < 4; ++kk) {
                short8 bfr = *(const short8*)&Ks[(fn * 16 + lr) * LDK + kk * 32 + lg * 8];
                s[fn] = __builtin_amdgcn_mfma_f32_16x16x32_bf16(qf[kk], bfr, s[fn], 0, 0, 0);
            }

        // online softmax (rows = lg*4+j, reduce across 16 lanes of the group)
        float mnew[4], alpha[4];
        for (int j = 0; j < 4; ++j) {
            float rm = fmaxf(fmaxf(s[0][j], s[1][j]), fmaxf(s[2][j], s[3][j]));
            for (int d = 1; d < 16; d <<= 1) rm = fmaxf(rm, __shfl_xor(rm, d));
            mnew[j] = fmaxf(m_i[j], rm);
            alpha[j] = __expf(m_i[j] - mnew[j]);
        }
        float p[4][4];
        for (int fn = 0; fn < 4; ++fn)
            for (int j = 0; j < 4; ++j)
                p[fn][j] = __expf(s[fn][j] - mnew[j]);
        for (int j = 0; j < 4; ++j) {
            float sum = p[0][j] + p[1][j] + p[2][j] + p[3][j];
            for (int d = 1; d < 16; d <<= 1) sum += __shfl_xor(sum, d);
            l_i[j] = l_i[j] * alpha[j] + sum;
            m_i[j] = mnew[j];
        }
        for (int db = 0; db < 8; ++db)
            for (int j = 0; j < 4; ++j)
                o[db][j] *= alpha[j];

        // P -> LDS (bf16), per-wave area
        for (int fn = 0; fn < 4; ++fn)
            for (int j = 0; j < 4; ++j)
                Pl[w][(lg * 4 + j) * LDP + fn * 16 + lr] = f2bf(p[fn][j]);

        // O += P V
        short8 pf0 = *(const short8*)&Pl[w][lr * LDP + lg * 8];
        short8 pf1 = *(const short8*)&Pl[w][lr * LDP + 32 + lg * 8];
        for (int db = 0; db < 8; ++db) {
            short8 v0 = *(const short8*)&Vts[(db * 16 + lr) * LDV + lg * 8];
            short8 v1 = *(const short8*)&Vts[(db * 16 + lr) * LDV + 32 + lg * 8];
            o[db] = __builtin_amdgcn_mfma_f32_16x16x32_bf16(pf0, v0, o[db], 0, 0, 0);
            o[db] = __builtin_amdgcn_mfma_f32_16x16x32_bf16(pf1, v1, o[db], 0, 0, 0);
        }
    }

    // normalize and store fp32
    for (int db = 0; db < 8; ++db)
        for (int j = 0; j < 4; ++j) {
            int row = q0 + w * 16 + lg * 4 + j;
            int col = h * DHEAD + db * 16 + lr;
            AO[(size_t)(b * SEQ + row) * 1024 + col] = o[db][j] / l_i[j];
        }
}

// ---------------------------------------------------------------------------
// Kernel 4: residual blend + LayerNorm, in place on d_out.
// x = AO*0.1 + q*0.9 ; out = (x-mu)*rsqrt(var+eps)*gamma + beta
// ---------------------------------------------------------------------------
__global__ __launch_bounds__(256) void ln_kernel(float* __restrict__ AO,
                                                 const float* __restrict__ qin,
                                                 const float* __restrict__ gamma,
                                                 const float* __restrict__ beta,
                                                 float* __restrict__ out) {
    __shared__ float red[8];
    int row = blockIdx.x;
    int t = threadIdx.x;
    size_t base = (size_t)row * 1024 + t * 4;

    float4 a = *(const float4*)&AO[base];
    float4 qq = *(const float4*)&qin[base];
    float x0 = a.x * 0.1f + qq.x * 0.9f;
    float x1 = a.y * 0.1f + qq.y * 0.9f;
    float x2 = a.z * 0.1f + qq.z * 0.9f;
    float x3 = a.w * 0.1f + qq.w * 0.9f;

    float s  = x0 + x1 + x2 + x3;
    float s2 = x0 * x0 + x1 * x1 + x2 * x2 + x3 * x3;
    for (int d = 1; d < 64; d <<= 1) {
        s  += __shfl_xor(s, d);
        s2 += __shfl_xor(s2, d);
    }
    int w = t >> 6, lane = t & 63;
    if (lane == 0) { red[w] = s; red[4 + w] = s2; }
    __syncthreads();
    s  = red[0] + red[1] + red[2] + red[3];
    s2 = red[4] + red[5] + red[6] + red[7];

    float mu   = s * (1.f / 1024.f);
    float var  = s2 * (1.f / 1024.f) - mu * mu;
    float rstd = rsqrtf(var + 1e-5f);

    float4 g  = *(const float4*)&gamma[t * 4];
    float4 be = *(const float4*)&beta[t * 4];
    float4 o;
    o.x = (x0 - mu) * rstd * g.x + be.x;
    o.y = (x1 - mu) * rstd * g.y + be.y;
    o.z = (x2 - mu) * rstd * g.z + be.z;
    o.w = (x3 - mu) * rstd * g.w + be.w;
    *(float4*)&out[base] = o;
}

// ---------------------------------------------------------------------------
extern "C" void kernel_launch(void* const* d_in, const int* in_sizes, int n_in,
                              void* d_out, int out_size, void* d_ws, size_t ws_size,
                              hipStream_t stream) {
    const float* q     = (const float*)d_in[0];
    const float* k     = (const float*)d_in[1];
    const float* Wq    = (const float*)d_in[2];
    const float* bq    = (const float*)d_in[3];
    const float* Wk    = (const float*)d_in[4];
    const float* bk    = (const float*)d_in[5];
    const float* gamma = (const float*)d_in[6];
    const float* beta  = (const float*)d_in[7];
    float* out = (float*)d_out;

    char* ws = (char*)d_ws;
    u16* WqT = (u16*)ws;                             // 2 MB
    u16* WkT = (u16*)(ws + (size_t)(2  << 20));      // 2 MB
    u16* Qb  = (u16*)(ws + (size_t)(4  << 20));      // 16 MB
    u16* Kb  = (u16*)(ws + (size_t)(20 << 20));      // 16 MB
    u16* Vt  = (u16*)(ws + (size_t)(36 << 20));      // 16 MB  (total 52 MB)

    // 1) transposes/converts: Wq, Wk, and per-batch V^T
    transpose_conv<<<dim3(32, 32, 2 + BATCH), dim3(32, 8), 0, stream>>>(Wq, Wk, k, WqT, WkT, Vt);

    // 2) projections (Q pre-scaled by 1/sqrt(DH))
    gemm_bias<<<dim3(8, 64), 256, 0, stream>>>(q, WqT, bq, Qb, 0.08838834764831845f);
    gemm_bias<<<dim3(8, 64), 256, 0, stream>>>(k, WkT, bk, Kb, 1.0f);

    // 3) attention -> d_out (fp32, pre-LN)
    attn_kernel<<<dim3(16, 64), 256, 0, stream>>>(Qb, Kb, Vt, out);

    // 4) residual + layernorm in place
    ln_kernel<<<8192, 256, 0, stream>>>(out, q, gamma, beta, out);
}

// Round 2
// 189.638 us; speedup vs baseline: 1.4493x; 1.4493x over previous
//
#include <hip/hip_runtime.h>
#include <hip/hip_bf16.h>
#include <cstdint>

// Problem constants
#define BATCH 8
#define SEQ   1024          // LQ == LK
#define DMODEL 1024
#define NHEAD 8
#define DHEAD 128
#define MROWS (BATCH * SEQ) // 8192

using short8 = __attribute__((ext_vector_type(8))) short;
using f32x4  = __attribute__((ext_vector_type(4))) float;
typedef unsigned short u16;

__device__ inline u16 f2bf(float f) {
    union { float f; uint32_t u; } v; v.f = f;
    uint32_t r = (v.u + 0x7FFFu + ((v.u >> 16) & 1u)) >> 16;
    return (u16)r;
}

// async global->LDS, 16B per lane. LDS dest must be wave-uniform base; HW adds lane*16.
#define GLL16(g, l)                                                                        \
    __builtin_amdgcn_global_load_lds((__attribute__((address_space(1))) const uint32_t*)(g), \
                                     (__attribute__((address_space(3))) uint32_t*)(l), 16, 0, 0)

// ---------------------------------------------------------------------------
// Kernel 1: transpose+convert fp32 [1024x1024] -> bf16 [1024x1024]^T
// z=0: Wq -> WqT ; z=1: Wk -> WkT ; z>=2: k[b] -> Vt[b]  (Vt[b][d][key])
// ---------------------------------------------------------------------------
__global__ void transpose_conv(const float* __restrict__ Wq,
                               const float* __restrict__ Wk,
                               const float* __restrict__ kin,
                               u16* __restrict__ WqT,
                               u16* __restrict__ WkT,
                               u16* __restrict__ Vt) {
    __shared__ float tile[32][33];
    int z = blockIdx.z;
    const float* src;
    u16* dst;
    if (z == 0)      { src = Wq; dst = WqT; }
    else if (z == 1) { src = Wk; dst = WkT; }
    else {
        src = kin + (size_t)(z - 2) * DMODEL * SEQ;
        dst = Vt  + (size_t)(z - 2) * DMODEL * SEQ;
    }
    int x  = blockIdx.x * 32 + threadIdx.x;
    int y0 = blockIdx.y * 32;
    for (int i = threadIdx.y; i < 32; i += 8)
        tile[i][threadIdx.x] = src[(size_t)(y0 + i) * 1024 + x];
    __syncthreads();
    int xo  = y0 + threadIdx.x;
    int yo0 = blockIdx.x * 32;
    for (int i = threadIdx.y; i < 32; i += 8)
        dst[(size_t)(yo0 + i) * 1024 + xo] = f2bf(tile[threadIdx.x][i]);
}

// ---------------------------------------------------------------------------
// Kernel 2: GEMM  Out[m][n] = (A[m][:] . BT[n][:] + bias[n]) * scale  -> bf16
// (unchanged this round)
// ---------------------------------------------------------------------------
#define LDA 40
__global__ __launch_bounds__(256) void gemm_bias(const float* __restrict__ A,
                                                 const u16* __restrict__ BT,
                                                 const float* __restrict__ bias,
                                                 u16* __restrict__ Out,
                                                 float scale) {
    __shared__ __align__(16) u16 As[128 * LDA];
    __shared__ __align__(16) u16 Bs[128 * LDA];
    int m0 = blockIdx.y * 128;
    int n0 = blockIdx.x * 128;
    int t = threadIdx.x;
    int lane = t & 63, w = t >> 6;
    int wm = w >> 1, wn = w & 1;
    int lr = lane & 15, lg = lane >> 4;

    f32x4 acc[4][4] = {};

    for (int k0 = 0; k0 < DMODEL; k0 += 32) {
        {
            int row = t >> 3;
            int c4  = (t & 7) * 4;
            for (int i = 0; i < 4; ++i) {
                const float4 v = *(const float4*)&A[(size_t)(m0 + row + i * 32) * 1024 + k0 + c4];
                uint2 pk;
                pk.x = (uint32_t)f2bf(v.x) | ((uint32_t)f2bf(v.y) << 16);
                pk.y = (uint32_t)f2bf(v.z) | ((uint32_t)f2bf(v.w) << 16);
                *(uint2*)&As[(row + i * 32) * LDA + c4] = pk;
            }
        }
        {
            int row = t >> 2;
            int c8  = (t & 3) * 8;
            for (int i = 0; i < 2; ++i) {
                uint4 v = *(const uint4*)&BT[(size_t)(n0 + row + i * 64) * 1024 + k0 + c8];
                *(uint4*)&Bs[(row + i * 64) * LDA + c8] = v;
            }
        }
        __syncthreads();
        short8 af[4], bf[4];
        for (int fm = 0; fm < 4; ++fm)
            af[fm] = *(const short8*)&As[(wm * 64 + fm * 16 + lr) * LDA + lg * 8];
        for (int fn = 0; fn < 4; ++fn)
            bf[fn] = *(const short8*)&Bs[(wn * 64 + fn * 16 + lr) * LDA + lg * 8];
        for (int fm = 0; fm < 4; ++fm)
            for (int fn = 0; fn < 4; ++fn)
                acc[fm][fn] = __builtin_amdgcn_mfma_f32_16x16x32_bf16(af[fm], bf[fn], acc[fm][fn], 0, 0, 0);
        __syncthreads();
    }
    for (int fm = 0; fm < 4; ++fm)
        for (int fn = 0; fn < 4; ++fn)
            for (int j = 0; j < 4; ++j) {
                int row = m0 + wm * 64 + fm * 16 + lg * 4 + j;
                int col = n0 + wn * 64 + fn * 16 + lr;
                float v = (acc[fm][fn][j] + bias[col]) * scale;
                Out[(size_t)row * 1024 + col] = f2bf(v);
            }
}

// ---------------------------------------------------------------------------
// Kernel 3: flash attention, restructured.
//   - 8 waves / block, 128 q-rows (wave: 16 rows), one (b,h) per block
//   - double-buffered K/V staging via global_load_lds, issue-before-compute
//   - linear LDS + XOR chunk swizzle (pre-swizzled global source)
//   - XCD-aware block swizzle: all 8 q-tiles of a head on one XCD
// ---------------------------------------------------------------------------
__global__ __launch_bounds__(512, 4) void attn_kernel(const u16* __restrict__ Qb,
                                                      const u16* __restrict__ Kb,
                                                      const u16* __restrict__ Vt,
                                                      float* __restrict__ AO) {
    __shared__ __align__(16) u16 Kbuf[2][64 * 128];   // 32 KB
    __shared__ __align__(16) u16 Vbuf[2][128 * 64];   // 32 KB
    __shared__ __align__(16) u16 Pl[8][16 * 64];      // 16 KB

    // XCD swizzle: 512 blocks, 8 XCDs -> 64 consecutive swz per XCD = 8 full heads
    int bid = blockIdx.x;
    int swz = (bid & 7) * 64 + (bid >> 3);
    int bh  = swz >> 3;          // 0..63
    int qt  = swz & 7;           // 0..7
    int b = bh >> 3, h = bh & 7;
    int q0 = qt * 128;

    int t = threadIdx.x, lane = t & 63, w = t >> 6;
    int lr = lane & 15, lg = lane >> 4;

    // Q fragments for this wave's 16 rows (pre-scaled by 1/sqrt(DH))
    short8 qf[4];
    {
        size_t qbase = (size_t)(b * SEQ + q0 + w * 16 + lr) * 1024 + h * DHEAD;
#pragma unroll
        for (int kk = 0; kk < 4; ++kk)
            qf[kk] = *(const short8*)&Qb[qbase + kk * 32 + lg * 8];
    }

    float m_i[4], l_i[4];
    f32x4 o[8] = {};
#pragma unroll
    for (int j = 0; j < 4; ++j) { m_i[j] = -1e30f; l_i[j] = 0.f; }

    u16* Pw = &Pl[w][0];

    // staging: per wave 2 K-issues + 2 V-issues of 1KB each, pre-swizzled source
#define STAGE(nb, kk0)                                                                   \
    {                                                                                    \
        _Pragma("unroll")                                                                \
        for (int i = 0; i < 2; ++i) {                                                    \
            int g = (w * 2 + i) * 64 + lane;                                             \
            int row = g >> 4, cp = g & 15;                                               \
            int c = cp ^ (row & 7);                                                      \
            const u16* src = Kb + ((size_t)(b * SEQ + (kk0) + row) * 1024 + h * 128 + c * 8); \
            GLL16(src, &Kbuf[nb][(w * 2 + i) * 512]);                                    \
        }                                                                                \
        _Pragma("unroll")                                                                \
        for (int i = 0; i < 2; ++i) {                                                    \
            int g = (w * 2 + i) * 64 + lane;                                             \
            int d = g >> 3, cp = g & 7;                                                  \
            int c = cp ^ (d & 7);                                                        \
            const u16* src = Vt + ((size_t)(bh * 128 + d) * 1024 + (kk0) + c * 8);       \
            GLL16(src, &Vbuf[nb][(w * 2 + i) * 512]);                                    \
        }                                                                                \
    }

    STAGE(0, 0);
    __syncthreads();   // vmcnt(0) drain: tile 0 resident

    int cur = 0;
    for (int k0 = 0; k0 < SEQ; k0 += 64) {
        // issue next tile's loads first: in flight during this tile's compute
        if (k0 + 64 < SEQ) STAGE(cur ^ 1, k0 + 64);

        // ---- S = Q K^T  (16 rows x 64 keys per wave) ----
        const u16* Kc = &Kbuf[cur][0];
        f32x4 s[4] = {};
        __builtin_amdgcn_s_setprio(1);
#pragma unroll
        for (int fn = 0; fn < 4; ++fn) {
            int row = fn * 16 + lr;
#pragma unroll
            for (int kk = 0; kk < 4; ++kk) {
                short8 bfr = *(const short8*)&Kc[row * 128 + (((kk * 4 + lg) ^ (lr & 7)) << 3)];
                s[fn] = __builtin_amdgcn_mfma_f32_16x16x32_bf16(qf[kk], bfr, s[fn], 0, 0, 0);
            }
        }
        __builtin_amdgcn_s_setprio(0);

        // ---- online softmax (rows = lg*4+j, keys across lr and fn) ----
        float mnew[4], alpha[4];
#pragma unroll
        for (int j = 0; j < 4; ++j) {
            float rm = fmaxf(fmaxf(s[0][j], s[1][j]), fmaxf(s[2][j], s[3][j]));
#pragma unroll
            for (int d = 1; d < 16; d <<= 1) rm = fmaxf(rm, __shfl_xor(rm, d));
            mnew[j] = fmaxf(m_i[j], rm);
            alpha[j] = __expf(m_i[j] - mnew[j]);
        }
        float p[4][4];
#pragma unroll
        for (int fn = 0; fn < 4; ++fn)
#pragma unroll
            for (int j = 0; j < 4; ++j)
                p[fn][j] = __expf(s[fn][j] - mnew[j]);
#pragma unroll
        for (int j = 0; j < 4; ++j) {
            float sum = p[0][j] + p[1][j] + p[2][j] + p[3][j];
#pragma unroll
            for (int d = 1; d < 16; d <<= 1) sum += __shfl_xor(sum, d);
            l_i[j] = l_i[j] * alpha[j] + sum;
            m_i[j] = mnew[j];
        }
#pragma unroll
        for (int db = 0; db < 8; ++db)
#pragma unroll
            for (int j = 0; j < 4; ++j)
                o[db][j] *= alpha[j];

        // ---- P -> LDS (bf16, per-wave, XOR-swizzled) ----
#pragma unroll
        for (int fn = 0; fn < 4; ++fn)
#pragma unroll
            for (int j = 0; j < 4; ++j) {
                int row = lg * 4 + j, col = fn * 16 + lr;
                int cs = (col >> 3) ^ (row & 7);
                Pw[row * 64 + (cs << 3) + (col & 7)] = f2bf(p[fn][j]);
            }

        // ---- O += P V ----
        const u16* Vc = &Vbuf[cur][0];
        short8 pf0 = *(const short8*)&Pw[lr * 64 + ((lg ^ (lr & 7)) << 3)];
        short8 pf1 = *(const short8*)&Pw[lr * 64 + (((4 + lg) ^ (lr & 7)) << 3)];
        __builtin_amdgcn_s_setprio(1);
#pragma unroll
        for (int db = 0; db < 8; ++db) {
            int vrow = db * 16 + lr;
            short8 v0 = *(const short8*)&Vc[vrow * 64 + ((lg ^ (lr & 7)) << 3)];
            short8 v1 = *(const short8*)&Vc[vrow * 64 + (((4 + lg) ^ (lr & 7)) << 3)];
            o[db] = __builtin_amdgcn_mfma_f32_16x16x32_bf16(pf0, v0, o[db], 0, 0, 0);
            o[db] = __builtin_amdgcn_mfma_f32_16x16x32_bf16(pf1, v1, o[db], 0, 0, 0);
        }
        __builtin_amdgcn_s_setprio(0);

        __syncthreads();   // drains vmcnt(0): next tile resident; LDS reads of cur done
        cur ^= 1;
    }

    // normalize and store fp32
#pragma unroll
    for (int db = 0; db < 8; ++db)
#pragma unroll
        for (int j = 0; j < 4; ++j) {
            int row = q0 + w * 16 + lg * 4 + j;
            int col = h * DHEAD + db * 16 + lr;
            AO[(size_t)(b * SEQ + row) * 1024 + col] = o[db][j] / l_i[j];
        }
#undef STAGE
}

// ---------------------------------------------------------------------------
// Kernel 4: residual blend + LayerNorm, in place on d_out. (unchanged)
// ---------------------------------------------------------------------------
__global__ __launch_bounds__(256) void ln_kernel(float* __restrict__ AO,
                                                 const float* __restrict__ qin,
                                                 const float* __restrict__ gamma,
                                                 const float* __restrict__ beta,
                                                 float* __restrict__ out) {
    __shared__ float red[8];
    int row = blockIdx.x;
    int t = threadIdx.x;
    size_t base = (size_t)row * 1024 + t * 4;

    float4 a = *(const float4*)&AO[base];
    float4 qq = *(const float4*)&qin[base];
    float x0 = a.x * 0.1f + qq.x * 0.9f;
    float x1 = a.y * 0.1f + qq.y * 0.9f;
    float x2 = a.z * 0.1f + qq.z * 0.9f;
    float x3 = a.w * 0.1f + qq.w * 0.9f;

    float s  = x0 + x1 + x2 + x3;
    float s2 = x0 * x0 + x1 * x1 + x2 * x2 + x3 * x3;
    for (int d = 1; d < 64; d <<= 1) {
        s  += __shfl_xor(s, d);
        s2 += __shfl_xor(s2, d);
    }
    int w = t >> 6, lane = t & 63;
    if (lane == 0) { red[w] = s; red[4 + w] = s2; }
    __syncthreads();
    s  = red[0] + red[1] + red[2] + red[3];
    s2 = red[4] + red[5] + red[6] + red[7];

    float mu   = s * (1.f / 1024.f);
    float var  = s2 * (1.f / 1024.f) - mu * mu;
    float rstd = rsqrtf(var + 1e-5f);

    float4 g  = *(const float4*)&gamma[t * 4];
    float4 be = *(const float4*)&beta[t * 4];
    float4 o;
    o.x = (x0 - mu) * rstd * g.x + be.x;
    o.y = (x1 - mu) * rstd * g.y + be.y;
    o.z = (x2 - mu) * rstd * g.z + be.z;
    o.w = (x3 - mu) * rstd * g.w + be.w;
    *(float4*)&out[base] = o;
}

// ---------------------------------------------------------------------------
extern "C" void kernel_launch(void* const* d_in, const int* in_sizes, int n_in,
                              void* d_out, int out_size, void* d_ws, size_t ws_size,
                              hipStream_t stream) {
    const float* q     = (const float*)d_in[0];
    const float* k     = (const float*)d_in[1];
    const float* Wq    = (const float*)d_in[2];
    const float* bq    = (const float*)d_in[3];
    const float* Wk    = (const float*)d_in[4];
    const float* bk    = (const float*)d_in[5];
    const float* gamma = (const float*)d_in[6];
    const float* beta  = (const float*)d_in[7];
    float* out = (float*)d_out;

    char* ws = (char*)d_ws;
    u16* WqT = (u16*)ws;                             // 2 MB
    u16* WkT = (u16*)(ws + (size_t)(2  << 20));      // 2 MB
    u16* Qb  = (u16*)(ws + (size_t)(4  << 20));      // 16 MB
    u16* Kb  = (u16*)(ws + (size_t)(20 << 20));      // 16 MB
    u16* Vt  = (u16*)(ws + (size_t)(36 << 20));      // 16 MB  (total 52 MB)

    // 1) transposes/converts: Wq, Wk, and per-batch V^T
    transpose_conv<<<dim3(32, 32, 2 + BATCH), dim3(32, 8), 0, stream>>>(Wq, Wk, k, WqT, WkT, Vt);

    // 2) projections (Q pre-scaled by 1/sqrt(DH))
    gemm_bias<<<dim3(8, 64), 256, 0, stream>>>(q, WqT, bq, Qb, 0.08838834764831845f);
    gemm_bias<<<dim3(8, 64), 256, 0, stream>>>(k, WkT, bk, Kb, 1.0f);

    // 3) attention -> d_out (fp32, pre-LN)
    attn_kernel<<<dim3(512), 512, 0, stream>>>(Qb, Kb, Vt, out);

    // 4) residual + layernorm in place
    ln_kernel<<<8192, 256, 0, stream>>>(out, q, gamma, beta, out);
}

// Round 3
// 151.410 us; speedup vs baseline: 1.8152x; 1.2525x over previous
//
#include <hip/hip_runtime.h>
#include <hip/hip_bf16.h>
#include <cstdint>

// Problem constants
#define BATCH 8
#define SEQ   1024          // LQ == LK
#define DMODEL 1024
#define NHEAD 8
#define DHEAD 128

using short8 = __attribute__((ext_vector_type(8))) short;
using f32x4  = __attribute__((ext_vector_type(4))) float;
typedef unsigned short u16;

__device__ inline u16 f2bf(float f) {
    union { float f; uint32_t u; } v; v.f = f;
    uint32_t r = (v.u + 0x7FFFu + ((v.u >> 16) & 1u)) >> 16;
    return (u16)r;
}

// async global->LDS, 16B per lane. LDS dest is wave-uniform base; HW adds lane*16.
#define GLL16(g, l)                                                                        \
    __builtin_amdgcn_global_load_lds((__attribute__((address_space(1))) const uint32_t*)(g), \
                                     (__attribute__((address_space(3))) uint32_t*)(l), 16, 0, 0)

// ---------------------------------------------------------------------------
// Kernel 0: convert q,k (fp32) -> bf16 into d_out scratch (qb | kb)
// ---------------------------------------------------------------------------
__global__ __launch_bounds__(256) void conv_bf16(const float* __restrict__ q,
                                                 const float* __restrict__ kin,
                                                 u16* __restrict__ dst) {
    size_t e = ((size_t)blockIdx.x * 256 + threadIdx.x) * 8;
    const size_t N1 = (size_t)8 * 1024 * 1024;
    const float* s = (e < N1) ? (q + e) : (kin + (e - N1));
    float4 a = *(const float4*)s;
    float4 b = *(const float4*)(s + 4);
    uint4 r;
    r.x = (uint32_t)f2bf(a.x) | ((uint32_t)f2bf(a.y) << 16);
    r.y = (uint32_t)f2bf(a.z) | ((uint32_t)f2bf(a.w) << 16);
    r.z = (uint32_t)f2bf(b.x) | ((uint32_t)f2bf(b.y) << 16);
    r.w = (uint32_t)f2bf(b.z) | ((uint32_t)f2bf(b.w) << 16);
    *(uint4*)(dst + e) = r;
}

// ---------------------------------------------------------------------------
// Kernel 1: transpose+convert fp32 [1024x1024] -> bf16 [1024x1024]^T
// z=0: Wq -> WqT ; z=1: Wk -> WkT ; z>=2: k[b] -> Vt[b]  (Vt[b][d][key])
// ---------------------------------------------------------------------------
__global__ void transpose_conv(const float* __restrict__ Wq,
                               const float* __restrict__ Wk,
                               const float* __restrict__ kin,
                               u16* __restrict__ WqT,
                               u16* __restrict__ WkT,
                               u16* __restrict__ Vt) {
    __shared__ float tile[32][33];
    int z = blockIdx.z;
    const float* src;
    u16* dst;
    if (z == 0)      { src = Wq; dst = WqT; }
    else if (z == 1) { src = Wk; dst = WkT; }
    else {
        src = kin + (size_t)(z - 2) * DMODEL * SEQ;
        dst = Vt  + (size_t)(z - 2) * DMODEL * SEQ;
    }
    int x  = blockIdx.x * 32 + threadIdx.x;
    int y0 = blockIdx.y * 32;
    for (int i = threadIdx.y; i < 32; i += 8)
        tile[i][threadIdx.x] = src[(size_t)(y0 + i) * 1024 + x];
    __syncthreads();
    int xo  = y0 + threadIdx.x;
    int yo0 = blockIdx.x * 32;
    for (int i = threadIdx.y; i < 32; i += 8)
        dst[(size_t)(yo0 + i) * 1024 + xo] = f2bf(tile[threadIdx.x][i]);
}

// ---------------------------------------------------------------------------
// Kernel 2: GEMM  Out[m][n] = (A[m][:] . BT[n][:] + bias[n]) * scale  -> bf16
// A bf16 [8192x1024], BT bf16 [1024(n) x 1024(k)], Out bf16 [8192x1024]
// m97 structure: 128x128 tile, BK=32, global_load_lds w16, dbuf, 1 barrier/iter
// Both-sides swizzle: LDS linear, inverse-swizzled global source, swizzled reads.
// ---------------------------------------------------------------------------
__global__ __launch_bounds__(256, 4) void gemm_bias(const u16* __restrict__ A,
                                                    const u16* __restrict__ BT,
                                                    const float* __restrict__ bias,
                                                    u16* __restrict__ Out,
                                                    float scale) {
    __shared__ __align__(16) u16 As[2][128 * 32];
    __shared__ __align__(16) u16 Bs[2][128 * 32];

    // XCD swizzle over 1D grid of 512: one XCD gets 8 contiguous m-tiles x all n
    int bid = blockIdx.x;
    int swz = (bid & 7) * 64 + (bid >> 3);
    int mt = swz >> 3, nt = swz & 7;
    int m0 = mt * 128, n0 = nt * 128;

    int t = threadIdx.x, lane = t & 63, w = t >> 6;
    int wm = w >> 1, wn = w & 1;
    int lr = lane & 15, lg = lane >> 4;

    // staging source pointers (inverse-swizzled): LDS granule L=(w*2+i)*64+lane
    const u16* pa[2];
    const u16* pb[2];
#pragma unroll
    for (int i = 0; i < 2; ++i) {
        int L = (w * 2 + i) * 64 + lane;   // 0..511 (16B granules of the 8KB tile)
        int rp = L >> 3, ss = L & 7;
        int u = ss ^ (rp & 7);
        int row = (rp << 1) | (u >> 2);
        int g = u & 3;
        pa[i] = A  + (size_t)(m0 + row) * 1024 + g * 8;
        pb[i] = BT + (size_t)(n0 + row) * 1024 + g * 8;
    }
    // swizzled fragment read offsets (u16 elems within one buffer)
    int aoff[4], boff[4];
#pragma unroll
    for (int f = 0; f < 4; ++f) {
        int rowA = wm * 64 + f * 16 + lr;
        int sA = (((rowA & 1) << 2) | lg) ^ ((rowA >> 1) & 7);
        aoff[f] = (rowA >> 1) * 64 + sA * 8;
        int rowB = wn * 64 + f * 16 + lr;
        int sB = (((rowB & 1) << 2) | lg) ^ ((rowB >> 1) & 7);
        boff[f] = (rowB >> 1) * 64 + sB * 8;
    }

    f32x4 acc[4][4] = {};

#define GSTAGE(buf)                                         \
    {                                                       \
        _Pragma("unroll")                                   \
        for (int i = 0; i < 2; ++i) {                       \
            GLL16(pa[i], &As[buf][(w * 2 + i) * 512]);      \
            GLL16(pb[i], &Bs[buf][(w * 2 + i) * 512]);      \
            pa[i] += 32;                                    \
            pb[i] += 32;                                    \
        }                                                   \
    }

    GSTAGE(0);
    __syncthreads();

    int cur = 0;
    for (int k0 = 0; k0 < DMODEL; k0 += 32) {
        if (k0 + 32 < DMODEL) GSTAGE(cur ^ 1);
        short8 af[4], bfr[4];
#pragma unroll
        for (int f = 0; f < 4; ++f) {
            af[f]  = *(const short8*)&As[cur][aoff[f]];
            bfr[f] = *(const short8*)&Bs[cur][boff[f]];
        }
        __builtin_amdgcn_s_setprio(1);
#pragma unroll
        for (int fm = 0; fm < 4; ++fm)
#pragma unroll
            for (int fn = 0; fn < 4; ++fn)
                acc[fm][fn] = __builtin_amdgcn_mfma_f32_16x16x32_bf16(af[fm], bfr[fn], acc[fm][fn], 0, 0, 0);
        __builtin_amdgcn_s_setprio(0);
        __syncthreads();
        cur ^= 1;
    }
#undef GSTAGE

    // epilogue: bias, scale, bf16 store
#pragma unroll
    for (int fn = 0; fn < 4; ++fn) {
        int col = n0 + wn * 64 + fn * 16 + lr;
        float bv = bias[col];
#pragma unroll
        for (int fm = 0; fm < 4; ++fm)
#pragma unroll
            for (int j = 0; j < 4; ++j) {
                int row = m0 + wm * 64 + fm * 16 + lg * 4 + j;
                Out[(size_t)row * 1024 + col] = f2bf((acc[fm][fn][j] + bv) * scale);
            }
    }
}

// ---------------------------------------------------------------------------
// Kernel 3: flash attention, swapped-QK^T structure.
//   S^T = mfma(A=K, B=Q): lane owns one q-row (lr) x 16 keys -> in-lane softmax
//   O^T = mfma(A=V^T, B=P^T): float4 output stores, scalar m/l per lane
//   defer-max (THR=8) skips O-rescale; dbuf global_load_lds staging.
// ---------------------------------------------------------------------------
__global__ __launch_bounds__(512, 4) void attn_kernel(const u16* __restrict__ Qb,
                                                      const u16* __restrict__ Kb,
                                                      const u16* __restrict__ Vt,
                                                      float* __restrict__ AO) {
    __shared__ __align__(16) u16 Kbuf[2][64 * 128];   // 32 KB
    __shared__ __align__(16) u16 Vbuf[2][128 * 64];   // 32 KB
    __shared__ __align__(16) u16 Pl[8][16 * 64];      // 16 KB

    // XCD swizzle: 512 blocks, 8 XCDs -> 64 consecutive swz per XCD = 8 full heads
    int bid = blockIdx.x;
    int swz = (bid & 7) * 64 + (bid >> 3);
    int bh  = swz >> 3;
    int qt  = swz & 7;
    int b = bh >> 3, h = bh & 7;
    int q0 = qt * 128;

    int t = threadIdx.x, lane = t & 63, w = t >> 6;
    int lr = lane & 15, lg = lane >> 4;

    // Q fragments (B-operand: col = q-row = lr), pre-scaled by 1/sqrt(DH)
    short8 qf[4];
    {
        size_t qbase = (size_t)(b * SEQ + q0 + w * 16 + lr) * 1024 + h * DHEAD;
#pragma unroll
        for (int kk = 0; kk < 4; ++kk)
            qf[kk] = *(const short8*)&Qb[qbase + kk * 32 + lg * 8];
    }

    float m_i = -1e30f, l_i = 0.f;
    f32x4 o[8] = {};
    u16* Pw = &Pl[w][0];
    const int pwrow = lr * 64;
    const int lx = lr & 7;

#define STAGE(nb, kk0)                                                                   \
    {                                                                                    \
        _Pragma("unroll")                                                                \
        for (int i = 0; i < 2; ++i) {                                                    \
            int g = (w * 2 + i) * 64 + lane;                                             \
            int row = g >> 4, cp = g & 15;                                               \
            int c = cp ^ (row & 7);                                                      \
            const u16* src = Kb + ((size_t)(b * SEQ + (kk0) + row) * 1024 + h * 128 + c * 8); \
            GLL16(src, &Kbuf[nb][(w * 2 + i) * 512]);                                    \
        }                                                                                \
        _Pragma("unroll")                                                                \
        for (int i = 0; i < 2; ++i) {                                                    \
            int g = (w * 2 + i) * 64 + lane;                                             \
            int d = g >> 3, cp = g & 7;                                                  \
            int c = cp ^ (d & 7);                                                        \
            const u16* src = Vt + ((size_t)(bh * 128 + d) * 1024 + (kk0) + c * 8);       \
            GLL16(src, &Vbuf[nb][(w * 2 + i) * 512]);                                    \
        }                                                                                \
    }

    STAGE(0, 0);
    __syncthreads();

    int cur = 0;
    for (int k0 = 0; k0 < SEQ; k0 += 64) {
        if (k0 + 64 < SEQ) STAGE(cur ^ 1, k0 + 64);

        // ---- S^T = K Q : s[fn][j] = S[q=lr][key = fn*16 + lg*4 + j] ----
        const u16* Kc = &Kbuf[cur][0];
        f32x4 s[4] = {};
        __builtin_amdgcn_s_setprio(1);
#pragma unroll
        for (int fn = 0; fn < 4; ++fn) {
            int krow = (fn * 16 + lr) * 128;
#pragma unroll
            for (int kk = 0; kk < 4; ++kk) {
                short8 kf = *(const short8*)&Kc[krow + (((kk * 4 + lg) ^ lx) << 3)];
                s[fn] = __builtin_amdgcn_mfma_f32_16x16x32_bf16(kf, qf[kk], s[fn], 0, 0, 0);
            }
        }
        __builtin_amdgcn_s_setprio(0);

        // ---- in-lane online softmax (q-row = lr; 16 keys local + 2 shfl) ----
        float pmax = s[0][0];
#pragma unroll
        for (int fn = 0; fn < 4; ++fn)
#pragma unroll
            for (int j = 0; j < 4; ++j) pmax = fmaxf(pmax, s[fn][j]);
        pmax = fmaxf(pmax, __shfl_xor(pmax, 16));
        pmax = fmaxf(pmax, __shfl_xor(pmax, 32));

        if (__any(pmax > m_i + 8.f)) {      // defer-max: rescale only on real growth
            float mnew = fmaxf(m_i, pmax);
            float alpha = __expf(m_i - mnew);
            m_i = mnew;
            l_i *= alpha;
#pragma unroll
            for (int db = 0; db < 8; ++db) o[db] *= alpha;
        }

        float p[4][4];
        float lsum = 0.f;
#pragma unroll
        for (int fn = 0; fn < 4; ++fn)
#pragma unroll
            for (int j = 0; j < 4; ++j) {
                p[fn][j] = __expf(s[fn][j] - m_i);
                lsum += p[fn][j];
            }
        lsum += __shfl_xor(lsum, 16);
        lsum += __shfl_xor(lsum, 32);
        l_i += lsum;

        // ---- P^T -> LDS: Pw[q=lr][key], 4x packed b64 writes ----
#pragma unroll
        for (int fn = 0; fn < 4; ++fn) {
            uint2 pk;
            pk.x = (uint32_t)f2bf(p[fn][0]) | ((uint32_t)f2bf(p[fn][1]) << 16);
            pk.y = (uint32_t)f2bf(p[fn][2]) | ((uint32_t)f2bf(p[fn][3]) << 16);
            int idx = pwrow + (((fn * 2 + (lg >> 1)) ^ lx) << 3) + ((lg & 1) << 2);
            *(uint2*)&Pw[idx] = pk;
        }

        // ---- O^T += V^T P^T ----
        const u16* Vc = &Vbuf[cur][0];
        short8 pf0 = *(const short8*)&Pw[pwrow + ((lg ^ lx) << 3)];
        short8 pf1 = *(const short8*)&Pw[pwrow + (((4 + lg) ^ lx) << 3)];
        __builtin_amdgcn_s_setprio(1);
#pragma unroll
        for (int db = 0; db < 8; ++db) {
            int vr = (db * 16 + lr) * 64;
            short8 v0 = *(const short8*)&Vc[vr + ((lg ^ lx) << 3)];
            short8 v1 = *(const short8*)&Vc[vr + (((4 + lg) ^ lx) << 3)];
            o[db] = __builtin_amdgcn_mfma_f32_16x16x32_bf16(v0, pf0, o[db], 0, 0, 0);
            o[db] = __builtin_amdgcn_mfma_f32_16x16x32_bf16(v1, pf1, o[db], 0, 0, 0);
        }
        __builtin_amdgcn_s_setprio(0);

        __syncthreads();   // drains vmcnt(0): next tile resident; LDS reads done
        cur ^= 1;
    }

    // normalize and store fp32 (float4: j indexes consecutive d)
    float inv = 1.f / l_i;
    size_t obase = (size_t)(b * SEQ + q0 + w * 16 + lr) * 1024 + h * DHEAD + lg * 4;
#pragma unroll
    for (int db = 0; db < 8; ++db) {
        float4 ov;
        ov.x = o[db][0] * inv;
        ov.y = o[db][1] * inv;
        ov.z = o[db][2] * inv;
        ov.w = o[db][3] * inv;
        *(float4*)&AO[obase + db * 16] = ov;
    }
#undef STAGE
}

// ---------------------------------------------------------------------------
// Kernel 4: residual blend + LayerNorm, in place on d_out.
// ---------------------------------------------------------------------------
__global__ __launch_bounds__(256) void ln_kernel(float* __restrict__ AO,
                                                 const float* __restrict__ qin,
                                                 const float* __restrict__ gamma,
                                                 const float* __restrict__ beta,
                                                 float* __restrict__ out) {
    __shared__ float red[8];
    int row = blockIdx.x;
    int t = threadIdx.x;
    size_t base = (size_t)row * 1024 + t * 4;

    float4 a = *(const float4*)&AO[base];
    float4 qq = *(const float4*)&qin[base];
    float x0 = a.x * 0.1f + qq.x * 0.9f;
    float x1 = a.y * 0.1f + qq.y * 0.9f;
    float x2 = a.z * 0.1f + qq.z * 0.9f;
    float x3 = a.w * 0.1f + qq.w * 0.9f;

    float s  = x0 + x1 + x2 + x3;
    float s2 = x0 * x0 + x1 * x1 + x2 * x2 + x3 * x3;
    for (int d = 1; d < 64; d <<= 1) {
        s  += __shfl_xor(s, d);
        s2 += __shfl_xor(s2, d);
    }
    int w = t >> 6, lane = t & 63;
    if (lane == 0) { red[w] = s; red[4 + w] = s2; }
    __syncthreads();
    s  = red[0] + red[1] + red[2] + red[3];
    s2 = red[4] + red[5] + red[6] + red[7];

    float mu   = s * (1.f / 1024.f);
    float var  = s2 * (1.f / 1024.f) - mu * mu;
    float rstd = rsqrtf(var + 1e-5f);

    float4 g  = *(const float4*)&gamma[t * 4];
    float4 be = *(const float4*)&beta[t * 4];
    float4 o;
    o.x = (x0 - mu) * rstd * g.x + be.x;
    o.y = (x1 - mu) * rstd * g.y + be.y;
    o.z = (x2 - mu) * rstd * g.z + be.z;
    o.w = (x3 - mu) * rstd * g.w + be.w;
    *(float4*)&out[base] = o;
}

// ---------------------------------------------------------------------------
extern "C" void kernel_launch(void* const* d_in, const int* in_sizes, int n_in,
                              void* d_out, int out_size, void* d_ws, size_t ws_size,
                              hipStream_t stream) {
    const float* q     = (const float*)d_in[0];
    const float* k     = (const float*)d_in[1];
    const float* Wq    = (const float*)d_in[2];
    const float* bq    = (const float*)d_in[3];
    const float* Wk    = (const float*)d_in[4];
    const float* bk    = (const float*)d_in[5];
    const float* gamma = (const float*)d_in[6];
    const float* beta  = (const float*)d_in[7];
    float* out = (float*)d_out;

    char* ws = (char*)d_ws;
    u16* WqT = (u16*)ws;                             // 2 MB
    u16* WkT = (u16*)(ws + (size_t)(2  << 20));      // 2 MB
    u16* Qb  = (u16*)(ws + (size_t)(4  << 20));      // 16 MB
    u16* Kb  = (u16*)(ws + (size_t)(20 << 20));      // 16 MB
    u16* Vt  = (u16*)(ws + (size_t)(36 << 20));      // 16 MB  (total 52 MB)

    // d_out doubles as bf16 scratch for q/k until attn overwrites it
    u16* qkb = (u16*)d_out;                          // qb [8M elems] | kb [8M elems]

    // 0) q,k -> bf16 (GEMM A operands)
    conv_bf16<<<8192, 256, 0, stream>>>(q, k, qkb);

    // 1) transposes/converts: Wq, Wk, and per-batch V^T
    transpose_conv<<<dim3(32, 32, 2 + BATCH), dim3(32, 8), 0, stream>>>(Wq, Wk, k, WqT, WkT, Vt);

    // 2) projections (Q pre-scaled by 1/sqrt(DH))
    gemm_bias<<<512, 256, 0, stream>>>(qkb, WqT, bq, Qb, 0.08838834764831845f);
    gemm_bias<<<512, 256, 0, stream>>>(qkb + (size_t)8 * 1024 * 1024, WkT, bk, Kb, 1.0f);

    // 3) attention -> d_out (fp32, pre-LN; overwrites the scratch)
    attn_kernel<<<512, 512, 0, stream>>>(Qb, Kb, Vt, out);

    // 4) residual + layernorm in place
    ln_kernel<<<8192, 256, 0, stream>>>(out, q, gamma, beta, out);
}

// Round 5
// 135.091 us; speedup vs baseline: 2.0345x; 1.1208x over previous
//
#include <hip/hip_runtime.h>
#include <hip/hip_bf16.h>
#include <cstdint>

// Problem constants
#define BATCH 8
#define SEQ   1024          // LQ == LK
#define DMODEL 1024
#define NHEAD 8
#define DHEAD 128

using short8 = __attribute__((ext_vector_type(8))) short;
using f32x4  = __attribute__((ext_vector_type(4))) float;
typedef unsigned short u16;

__device__ inline u16 f2bf(float f) {
    union { float f; uint32_t u; } v; v.f = f;
    uint32_t r = (v.u + 0x7FFFu + ((v.u >> 16) & 1u)) >> 16;
    return (u16)r;
}

// native 2^x (v_exp_f32)
__device__ inline float exp2_fast(float x) { return __builtin_amdgcn_exp2f(x); }

// packed f32x2 -> bf16x2 (RNE), low half = a
__device__ inline uint32_t cvtpk_bf16(float a, float b) {
    uint32_t r;
    asm("v_cvt_pk_bf16_f32 %0, %1, %2" : "=v"(r) : "v"(a), "v"(b));
    return r;
}

// async global->LDS, 16B per lane. LDS dest is wave-uniform base; HW adds lane*16.
#define GLL16(g, l)                                                                        \
    __builtin_amdgcn_global_load_lds((__attribute__((address_space(1))) const uint32_t*)(g), \
                                     (__attribute__((address_space(3))) uint32_t*)(l), 16, 0, 0)

// ---------------------------------------------------------------------------
// Kernel 0: convert q (fp32) -> bf16 (GEMM A operand), 8 elems/thread
// ---------------------------------------------------------------------------
__global__ __launch_bounds__(256) void conv_bf16(const float* __restrict__ q,
                                                 u16* __restrict__ dst) {
    size_t e = ((size_t)blockIdx.x * 256 + threadIdx.x) * 8;
    float4 a = *(const float4*)(q + e);
    float4 b = *(const float4*)(q + e + 4);
    uint4 r;
    r.x = (uint32_t)f2bf(a.x) | ((uint32_t)f2bf(a.y) << 16);
    r.y = (uint32_t)f2bf(a.z) | ((uint32_t)f2bf(a.w) << 16);
    r.z = (uint32_t)f2bf(b.x) | ((uint32_t)f2bf(b.y) << 16);
    r.w = (uint32_t)f2bf(b.z) | ((uint32_t)f2bf(b.w) << 16);
    *(uint4*)(dst + e) = r;
}

// ---------------------------------------------------------------------------
// Kernel 1: transpose+convert fp32 [1024x1024] -> bf16 [1024x1024]^T
// z=0: Wq -> WqT ; z=1: Wk -> WkT ; z>=2: k[b] -> Vt[b]  AND  k[b] -> kb[b]
// (kb = straight bf16 copy, fused to read k only once)
// ---------------------------------------------------------------------------
__global__ void transpose_conv(const float* __restrict__ Wq,
                               const float* __restrict__ Wk,
                               const float* __restrict__ kin,
                               u16* __restrict__ WqT,
                               u16* __restrict__ WkT,
                               u16* __restrict__ Vt,
                               u16* __restrict__ kb) {
    __shared__ float tile[32][33];
    int z = blockIdx.z;
    const float* src;
    u16* dst;
    u16* sdst = nullptr;
    if (z == 0)      { src = Wq; dst = WqT; }
    else if (z == 1) { src = Wk; dst = WkT; }
    else {
        src  = kin + (size_t)(z - 2) * DMODEL * SEQ;
        dst  = Vt  + (size_t)(z - 2) * DMODEL * SEQ;
        sdst = kb  + (size_t)(z - 2) * DMODEL * SEQ;
    }
    int x  = blockIdx.x * 32 + threadIdx.x;
    int y0 = blockIdx.y * 32;
    for (int i = threadIdx.y; i < 32; i += 8) {
        float v = src[(size_t)(y0 + i) * 1024 + x];
        tile[i][threadIdx.x] = v;
        if (sdst) sdst[(size_t)(y0 + i) * 1024 + x] = f2bf(v);
    }
    __syncthreads();
    int xo  = y0 + threadIdx.x;
    int yo0 = blockIdx.x * 32;
    for (int i = threadIdx.y; i < 32; i += 8)
        dst[(size_t)(yo0 + i) * 1024 + xo] = f2bf(tile[threadIdx.x][i]);
}

// ---------------------------------------------------------------------------
// Kernel 2: fused dual GEMM  Out[m][n] = (A[m][:] . BT[n][:] + bias[n]) * scale
// blocks 0..511: Q-projection (scale includes 1/sqrt(DH) * log2e for exp2-domain
// softmax); blocks 512..1023: K-projection (scale 1).
// m97 structure: 128x128 tile, BK=32, global_load_lds w16, dbuf, 1 barrier/iter.
// ---------------------------------------------------------------------------
__global__ __launch_bounds__(256, 4) void gemm_dual(const u16* __restrict__ Aq,
                                                    const u16* __restrict__ Ak,
                                                    const u16* __restrict__ BTq,
                                                    const u16* __restrict__ BTk,
                                                    const float* __restrict__ biasq,
                                                    const float* __restrict__ biask,
                                                    u16* __restrict__ Outq,
                                                    u16* __restrict__ Outk) {
    __shared__ __align__(16) u16 As[2][128 * 32];
    __shared__ __align__(16) u16 Bs[2][128 * 32];

    int bid = blockIdx.x;
    int half = bid >> 9;
    int b2 = bid & 511;
    const u16* A  = half ? Ak  : Aq;
    const u16* BT = half ? BTk : BTq;
    const float* bias = half ? biask : biasq;
    u16* Out = half ? Outk : Outq;
    // Q-scale carries log2e so attention softmax can run in exp2 domain
    float scale = half ? 1.0f : (0.08838834764831845f * 1.4426950408889634f);

    // XCD swizzle within each half (global XCD = bid%8 = b2%8 since 512%8==0)
    int swz = (b2 & 7) * 64 + (b2 >> 3);
    int mt = swz >> 3, nt = swz & 7;
    int m0 = mt * 128, n0 = nt * 128;

    int t = threadIdx.x, lane = t & 63, w = t >> 6;
    int wm = w >> 1, wn = w & 1;
    int lr = lane & 15, lg = lane >> 4;

    // staging source pointers (inverse-swizzled): LDS granule L=(w*2+i)*64+lane
    const u16* pa[2];
    const u16* pb[2];
#pragma unroll
    for (int i = 0; i < 2; ++i) {
        int L = (w * 2 + i) * 64 + lane;   // 0..511 (16B granules of the 8KB tile)
        int rp = L >> 3, ss = L & 7;
        int u = ss ^ (rp & 7);
        int row = (rp << 1) | (u >> 2);
        int g = u & 3;
        pa[i] = A  + (size_t)(m0 + row) * 1024 + g * 8;
        pb[i] = BT + (size_t)(n0 + row) * 1024 + g * 8;
    }
    // swizzled fragment read offsets (u16 elems within one buffer)
    int aoff[4], boff[4];
#pragma unroll
    for (int f = 0; f < 4; ++f) {
        int rowA = wm * 64 + f * 16 + lr;
        int sA = (((rowA & 1) << 2) | lg) ^ ((rowA >> 1) & 7);
        aoff[f] = (rowA >> 1) * 64 + sA * 8;
        int rowB = wn * 64 + f * 16 + lr;
        int sB = (((rowB & 1) << 2) | lg) ^ ((rowB >> 1) & 7);
        boff[f] = (rowB >> 1) * 64 + sB * 8;
    }

    f32x4 acc[4][4] = {};

#define GSTAGE(buf)                                         \
    {                                                       \
        _Pragma("unroll")                                   \
        for (int i = 0; i < 2; ++i) {                       \
            GLL16(pa[i], &As[buf][(w * 2 + i) * 512]);      \
            GLL16(pb[i], &Bs[buf][(w * 2 + i) * 512]);      \
            pa[i] += 32;                                    \
            pb[i] += 32;                                    \
        }                                                   \
    }

    GSTAGE(0);
    __syncthreads();

    int cur = 0;
    for (int k0 = 0; k0 < DMODEL; k0 += 32) {
        if (k0 + 32 < DMODEL) GSTAGE(cur ^ 1);
        short8 af[4], bfr[4];
#pragma unroll
        for (int f = 0; f < 4; ++f) {
            af[f]  = *(const short8*)&As[cur][aoff[f]];
            bfr[f] = *(const short8*)&Bs[cur][boff[f]];
        }
        __builtin_amdgcn_s_setprio(1);
#pragma unroll
        for (int fm = 0; fm < 4; ++fm)
#pragma unroll
            for (int fn = 0; fn < 4; ++fn)
                acc[fm][fn] = __builtin_amdgcn_mfma_f32_16x16x32_bf16(af[fm], bfr[fn], acc[fm][fn], 0, 0, 0);
        __builtin_amdgcn_s_setprio(0);
        __syncthreads();
        cur ^= 1;
    }
#undef GSTAGE

    // epilogue: bias, scale, bf16 store
#pragma unroll
    for (int fn = 0; fn < 4; ++fn) {
        int col = n0 + wn * 64 + fn * 16 + lr;
        float bv = bias[col];
#pragma unroll
        for (int fm = 0; fm < 4; ++fm)
#pragma unroll
            for (int j = 0; j < 4; ++j) {
                int row = m0 + wm * 64 + fm * 16 + lg * 4 + j;
                Out[(size_t)row * 1024 + col] = f2bf((acc[fm][fn][j] + bv) * scale);
            }
    }
}

// ---------------------------------------------------------------------------
// Kernel 3: flash attention, swapped-QK^T, exp2-domain softmax.
//   S^T = mfma(A=K, B=Q): lane owns one q-row (lr); Q pre-scaled by log2e/sqrt(DH)
//   p = exp2(s - m) == softmax numerator of original logits
//   O^T = mfma(A=V^T, B=P^T); defer-max THR = 8*log2e; dbuf global_load_lds.
// ---------------------------------------------------------------------------
__global__ __launch_bounds__(512, 4) void attn_kernel(const u16* __restrict__ Qb,
                                                      const u16* __restrict__ Kb,
                                                      const u16* __restrict__ Vt,
                                                      float* __restrict__ AO) {
    __shared__ __align__(16) u16 Kbuf[2][64 * 128];   // 32 KB
    __shared__ __align__(16) u16 Vbuf[2][128 * 64];   // 32 KB
    __shared__ __align__(16) u16 Pl[8][16 * 64];      // 16 KB

    // XCD swizzle: 512 blocks, 8 XCDs -> 64 consecutive swz per XCD = 8 full heads
    int bid = blockIdx.x;
    int swz = (bid & 7) * 64 + (bid >> 3);
    int bh  = swz >> 3;
    int qt  = swz & 7;
    int b = bh >> 3, h = bh & 7;
    int q0 = qt * 128;

    int t = threadIdx.x, lane = t & 63, w = t >> 6;
    int lr = lane & 15, lg = lane >> 4;

    // Q fragments (B-operand: col = q-row = lr)
    short8 qf[4];
    {
        size_t qbase = (size_t)(b * SEQ + q0 + w * 16 + lr) * 1024 + h * DHEAD;
#pragma unroll
        for (int kk = 0; kk < 4; ++kk)
            qf[kk] = *(const short8*)&Qb[qbase + kk * 32 + lg * 8];
    }

    float m_i = -1e30f, l_i = 0.f;
    f32x4 o[8] = {};
    u16* Pw = &Pl[w][0];
    const int pwrow = lr * 64;
    const int lx = lr & 7;

#define STAGE(nb, kk0)                                                                   \
    {                                                                                    \
        _Pragma("unroll")                                                                \
        for (int i = 0; i < 2; ++i) {                                                    \
            int g = (w * 2 + i) * 64 + lane;                                             \
            int row = g >> 4, cp = g & 15;                                               \
            int c = cp ^ (row & 7);                                                      \
            const u16* src = Kb + ((size_t)(b * SEQ + (kk0) + row) * 1024 + h * 128 + c * 8); \
            GLL16(src, &Kbuf[nb][(w * 2 + i) * 512]);                                    \
        }                                                                                \
        _Pragma("unroll")                                                                \
        for (int i = 0; i < 2; ++i) {                                                    \
            int g = (w * 2 + i) * 64 + lane;                                             \
            int d = g >> 3, cp = g & 7;                                                  \
            int c = cp ^ (d & 7);                                                        \
            const u16* src = Vt + ((size_t)(bh * 128 + d) * 1024 + (kk0) + c * 8);       \
            GLL16(src, &Vbuf[nb][(w * 2 + i) * 512]);                                    \
        }                                                                                \
    }

    STAGE(0, 0);
    __syncthreads();

    int cur = 0;
    for (int k0 = 0; k0 < SEQ; k0 += 64) {
        if (k0 + 64 < SEQ) STAGE(cur ^ 1, k0 + 64);

        // ---- S^T = K Q : s[fn][j] = S[q=lr][key = fn*16 + lg*4 + j] (log2 dom.)
        const u16* Kc = &Kbuf[cur][0];
        f32x4 s[4] = {};
        __builtin_amdgcn_s_setprio(1);
#pragma unroll
        for (int fn = 0; fn < 4; ++fn) {
            int krow = (fn * 16 + lr) * 128;
#pragma unroll
            for (int kk = 0; kk < 4; ++kk) {
                short8 kf = *(const short8*)&Kc[krow + (((kk * 4 + lg) ^ lx) << 3)];
                s[fn] = __builtin_amdgcn_mfma_f32_16x16x32_bf16(kf, qf[kk], s[fn], 0, 0, 0);
            }
        }
        __builtin_amdgcn_s_setprio(0);

        // ---- in-lane online softmax (q-row = lr; 16 keys local + 2 shfl) ----
        float pmax = s[0][0];
#pragma unroll
        for (int fn = 0; fn < 4; ++fn)
#pragma unroll
            for (int j = 0; j < 4; ++j) pmax = fmaxf(pmax, s[fn][j]);
        pmax = fmaxf(pmax, __shfl_xor(pmax, 16));
        pmax = fmaxf(pmax, __shfl_xor(pmax, 32));

        if (__any(pmax > m_i + 11.5416f)) {   // defer-max: 8 nats in log2 units
            float mnew = fmaxf(m_i, pmax);
            float alpha = exp2_fast(m_i - mnew);
            m_i = mnew;
            l_i *= alpha;
#pragma unroll
            for (int db = 0; db < 8; ++db) o[db] *= alpha;
        }

        float p[4][4];
        float lsum = 0.f;
#pragma unroll
        for (int fn = 0; fn < 4; ++fn)
#pragma unroll
            for (int j = 0; j < 4; ++j) {
                p[fn][j] = exp2_fast(s[fn][j] - m_i);
                lsum += p[fn][j];
            }
        lsum += __shfl_xor(lsum, 16);
        lsum += __shfl_xor(lsum, 32);
        l_i += lsum;

        // ---- P^T -> LDS: Pw[q=lr][key], packed b64 writes via v_cvt_pk ----
#pragma unroll
        for (int fn = 0; fn < 4; ++fn) {
            uint2 pk;
            pk.x = cvtpk_bf16(p[fn][0], p[fn][1]);
            pk.y = cvtpk_bf16(p[fn][2], p[fn][3]);
            int idx = pwrow + (((fn * 2 + (lg >> 1)) ^ lx) << 3) + ((lg & 1) << 2);
            *(uint2*)&Pw[idx] = pk;
        }

        // ---- O^T += V^T P^T ----
        const u16* Vc = &Vbuf[cur][0];
        short8 pf0 = *(const short8*)&Pw[pwrow + ((lg ^ lx) << 3)];
        short8 pf1 = *(const short8*)&Pw[pwrow + (((4 + lg) ^ lx) << 3)];
        __builtin_amdgcn_s_setprio(1);
#pragma unroll
        for (int db = 0; db < 8; ++db) {
            int vr = (db * 16 + lr) * 64;
            short8 v0 = *(const short8*)&Vc[vr + ((lg ^ lx) << 3)];
            short8 v1 = *(const short8*)&Vc[vr + (((4 + lg) ^ lx) << 3)];
            o[db] = __builtin_amdgcn_mfma_f32_16x16x32_bf16(v0, pf0, o[db], 0, 0, 0);
            o[db] = __builtin_amdgcn_mfma_f32_16x16x32_bf16(v1, pf1, o[db], 0, 0, 0);
        }
        __builtin_amdgcn_s_setprio(0);

        __syncthreads();   // drains vmcnt(0): next tile resident; LDS reads done
        cur ^= 1;
    }

    // normalize and store fp32 (float4: j indexes consecutive d)
    float inv = 1.f / l_i;
    size_t obase = (size_t)(b * SEQ + q0 + w * 16 + lr) * 1024 + h * DHEAD + lg * 4;
#pragma unroll
    for (int db = 0; db < 8; ++db) {
        float4 ov;
        ov.x = o[db][0] * inv;
        ov.y = o[db][1] * inv;
        ov.z = o[db][2] * inv;
        ov.w = o[db][3] * inv;
        *(float4*)&AO[obase + db * 16] = ov;
    }
#undef STAGE
}

// ---------------------------------------------------------------------------
// Kernel 4: residual blend + LayerNorm, in place on d_out.
// ---------------------------------------------------------------------------
__global__ __launch_bounds__(256) void ln_kernel(float* __restrict__ AO,
                                                 const float* __restrict__ qin,
                                                 const float* __restrict__ gamma,
                                                 const float* __restrict__ beta,
                                                 float* __restrict__ out) {
    __shared__ float red[8];
    int row = blockIdx.x;
    int t = threadIdx.x;
    size_t base = (size_t)row * 1024 + t * 4;

    float4 a = *(const float4*)&AO[base];
    float4 qq = *(const float4*)&qin[base];
    float x0 = a.x * 0.1f + qq.x * 0.9f;
    float x1 = a.y * 0.1f + qq.y * 0.9f;
    float x2 = a.z * 0.1f + qq.z * 0.9f;
    float x3 = a.w * 0.1f + qq.w * 0.9f;

    float s  = x0 + x1 + x2 + x3;
    float s2 = x0 * x0 + x1 * x1 + x2 * x2 + x3 * x3;
    for (int d = 1; d < 64; d <<= 1) {
        s  += __shfl_xor(s, d);
        s2 += __shfl_xor(s2, d);
    }
    int w = t >> 6, lane = t & 63;
    if (lane == 0) { red[w] = s; red[4 + w] = s2; }
    __syncthreads();
    s  = red[0] + red[1] + red[2] + red[3];
    s2 = red[4] + red[5] + red[6] + red[7];

    float mu   = s * (1.f / 1024.f);
    float var  = s2 * (1.f / 1024.f) - mu * mu;
    float rstd = rsqrtf(var + 1e-5f);

    float4 g  = *(const float4*)&gamma[t * 4];
    float4 be = *(const float4*)&beta[t * 4];
    float4 o;
    o.x = (x0 - mu) * rstd * g.x + be.x;
    o.y = (x1 - mu) * rstd * g.y + be.y;
    o.z = (x2 - mu) * rstd * g.z + be.z;
    o.w = (x3 - mu) * rstd * g.w + be.w;
    *(float4*)&out[base] = o;
}

// ---------------------------------------------------------------------------
extern "C" void kernel_launch(void* const* d_in, const int* in_sizes, int n_in,
                              void* d_out, int out_size, void* d_ws, size_t ws_size,
                              hipStream_t stream) {
    const float* q     = (const float*)d_in[0];
    const float* k     = (const float*)d_in[1];
    const float* Wq    = (const float*)d_in[2];
    const float* bq    = (const float*)d_in[3];
    const float* Wk    = (const float*)d_in[4];
    const float* bk    = (const float*)d_in[5];
    const float* gamma = (const float*)d_in[6];
    const float* beta  = (const float*)d_in[7];
    float* out = (float*)d_out;

    char* ws = (char*)d_ws;
    u16* WqT = (u16*)ws;                             // 2 MB
    u16* WkT = (u16*)(ws + (size_t)(2  << 20));      // 2 MB
    u16* Qb  = (u16*)(ws + (size_t)(4  << 20));      // 16 MB
    u16* Kb  = (u16*)(ws + (size_t)(20 << 20));      // 16 MB
    u16* Vt  = (u16*)(ws + (size_t)(36 << 20));      // 16 MB  (total 52 MB)

    // d_out doubles as bf16 scratch for q/k until attn overwrites it
    u16* qb = (u16*)d_out;                           // 8M elems
    u16* kb = qb + (size_t)8 * 1024 * 1024;          // 8M elems

    // 0) q -> bf16
    conv_bf16<<<4096, 256, 0, stream>>>(q, qb);

    // 1) W transposes + k -> (Vt, kb) in one pass over k
    transpose_conv<<<dim3(32, 32, 2 + BATCH), dim3(32, 8), 0, stream>>>(Wq, Wk, k, WqT, WkT, Vt, kb);

    // 2) both projections in one launch (Q pre-scaled by log2e/sqrt(DH))
    gemm_dual<<<1024, 256, 0, stream>>>(qb, kb, WqT, WkT, bq, bk, Qb, Kb);

    // 3) attention -> d_out (fp32, pre-LN; overwrites the scratch)
    attn_kernel<<<512, 512, 0, stream>>>(Qb, Kb, Vt, out);

    // 4) residual + layernorm in place
    ln_kernel<<<8192, 256, 0, stream>>>(out, q, gamma, beta, out);
}

// Round 6
// 130.722 us; speedup vs baseline: 2.1025x; 1.0334x over previous
//
#include <hip/hip_runtime.h>
#include <hip/hip_bf16.h>
#include <cstdint>

// Problem constants
#define BATCH 8
#define SEQ   1024          // LQ == LK
#define DMODEL 1024
#define NHEAD 8
#define DHEAD 128

using short8 = __attribute__((ext_vector_type(8))) short;
using f32x4  = __attribute__((ext_vector_type(4))) float;
typedef unsigned short u16;

__device__ inline u16 f2bf(float f) {
    union { float f; uint32_t u; } v; v.f = f;
    uint32_t r = (v.u + 0x7FFFu + ((v.u >> 16) & 1u)) >> 16;
    return (u16)r;
}

// native 2^x (v_exp_f32)
__device__ inline float exp2_fast(float x) { return __builtin_amdgcn_exp2f(x); }

// packed f32x2 -> bf16x2 (RNE), low half = a
__device__ inline uint32_t cvtpk_bf16(float a, float b) {
    uint32_t r;
    asm("v_cvt_pk_bf16_f32 %0, %1, %2" : "=v"(r) : "v"(a), "v"(b));
    return r;
}

// async global->LDS, 16B per lane. LDS dest is wave-uniform base; HW adds lane*16.
#define GLL16(g, l)                                                                        \
    __builtin_amdgcn_global_load_lds((__attribute__((address_space(1))) const uint32_t*)(g), \
                                     (__attribute__((address_space(3))) uint32_t*)(l), 16, 0, 0)

// ---------------------------------------------------------------------------
// Kernel 1: transpose+convert fp32 [1024x1024] -> bf16 [1024x1024]^T
// z=0: Wq -> WqT ; z=1: Wk -> WkT ; z>=2: k[b] -> Vt[b]  (Vt[b][d][key])
// ---------------------------------------------------------------------------
__global__ void transpose_conv(const float* __restrict__ Wq,
                               const float* __restrict__ Wk,
                               const float* __restrict__ kin,
                               u16* __restrict__ WqT,
                               u16* __restrict__ WkT,
                               u16* __restrict__ Vt) {
    __shared__ float tile[32][33];
    int z = blockIdx.z;
    const float* src;
    u16* dst;
    if (z == 0)      { src = Wq; dst = WqT; }
    else if (z == 1) { src = Wk; dst = WkT; }
    else {
        src = kin + (size_t)(z - 2) * DMODEL * SEQ;
        dst = Vt  + (size_t)(z - 2) * DMODEL * SEQ;
    }
    int x  = blockIdx.x * 32 + threadIdx.x;
    int y0 = blockIdx.y * 32;
    for (int i = threadIdx.y; i < 32; i += 8)
        tile[i][threadIdx.x] = src[(size_t)(y0 + i) * 1024 + x];
    __syncthreads();
    int xo  = y0 + threadIdx.x;
    int yo0 = blockIdx.x * 32;
    for (int i = threadIdx.y; i < 32; i += 8)
        dst[(size_t)(yo0 + i) * 1024 + xo] = f2bf(tile[threadIdx.x][i]);
}

// ---------------------------------------------------------------------------
// Kernel 2: fused dual GEMM, A read directly as fp32 (reg-staged fp32->bf16,
// T14-style issue-early/write-late); B via global_load_lds. 128x128 tile,
// BK=32, dbuf, 1 barrier/iter. blocks 0..511: Q-proj (scale = log2e/sqrt(DH));
// 512..1023: K-proj.
// ---------------------------------------------------------------------------
__global__ __launch_bounds__(256, 4) void gemm_dual(const float* __restrict__ Aqf,
                                                    const float* __restrict__ Akf,
                                                    const u16* __restrict__ BTq,
                                                    const u16* __restrict__ BTk,
                                                    const float* __restrict__ biasq,
                                                    const float* __restrict__ biask,
                                                    u16* __restrict__ Outq,
                                                    u16* __restrict__ Outk) {
    __shared__ __align__(16) u16 As[2][128 * 32];
    __shared__ __align__(16) u16 Bs[2][128 * 32];

    int bid = blockIdx.x;
    int half = bid >> 9;
    int b2 = bid & 511;
    const float* A  = half ? Akf : Aqf;
    const u16* BT   = half ? BTk : BTq;
    const float* bias = half ? biask : biasq;
    u16* Out = half ? Outk : Outq;
    // Q-scale carries log2e so attention softmax runs in exp2 domain
    float scale = half ? 1.0f : (0.08838834764831845f * 1.4426950408889634f);

    // XCD swizzle within each half (XCD = bid%8 = b2%8 since 512%8==0)
    int swz = (b2 & 7) * 64 + (b2 >> 3);
    int mt = swz >> 3, nt = swz & 7;
    int m0 = mt * 128, n0 = nt * 128;

    int t = threadIdx.x, lane = t & 63, w = t >> 6;
    int wm = w >> 1, wn = w & 1;
    int lr = lane & 15, lg = lane >> 4;

    // staging sources (inverse-swizzled): LDS granule L = (w*2+i)*64+lane
    const float* pa[2];
    const u16* pb[2];
    int ldsoff[2];
#pragma unroll
    for (int i = 0; i < 2; ++i) {
        int L = (w * 2 + i) * 64 + lane;   // 16B granules of the 8KB tile
        int rp = L >> 3, ss = L & 7;
        int u = ss ^ (rp & 7);
        int row = (rp << 1) | (u >> 2);
        int g = u & 3;
        pa[i] = A  + (size_t)(m0 + row) * 1024 + g * 8;
        pb[i] = BT + (size_t)(n0 + row) * 1024 + g * 8;
        ldsoff[i] = L * 8;                 // u16 units
    }
    // swizzled fragment read offsets (u16 elems within one buffer)
    int aoff[4], boff[4];
#pragma unroll
    for (int f = 0; f < 4; ++f) {
        int rowA = wm * 64 + f * 16 + lr;
        int sA = (((rowA & 1) << 2) | lg) ^ ((rowA >> 1) & 7);
        aoff[f] = (rowA >> 1) * 64 + sA * 8;
        int rowB = wn * 64 + f * 16 + lr;
        int sB = (((rowB & 1) << 2) | lg) ^ ((rowB >> 1) & 7);
        boff[f] = (rowB >> 1) * 64 + sB * 8;
    }

    f32x4 acc[4][4] = {};

    // prologue: stage tile 0 (A reg-staged, B async)
#pragma unroll
    for (int i = 0; i < 2; ++i) {
        float4 v0 = *(const float4*)pa[i];
        float4 v1 = *(const float4*)(pa[i] + 4);
        uint4 r;
        r.x = cvtpk_bf16(v0.x, v0.y);
        r.y = cvtpk_bf16(v0.z, v0.w);
        r.z = cvtpk_bf16(v1.x, v1.y);
        r.w = cvtpk_bf16(v1.z, v1.w);
        *(uint4*)&As[0][ldsoff[i]] = r;
        GLL16(pb[i], &Bs[0][(w * 2 + i) * 512]);
        pa[i] += 32;
        pb[i] += 32;
    }
    __syncthreads();

    int cur = 0;
    for (int k0 = 0; k0 < DMODEL; k0 += 32) {
        bool more = (k0 + 32 < DMODEL);
        float4 va[2], vb[2];
        if (more) {
#pragma unroll
            for (int i = 0; i < 2; ++i) {
                GLL16(pb[i], &Bs[cur ^ 1][(w * 2 + i) * 512]);
                va[i] = *(const float4*)pa[i];
                vb[i] = *(const float4*)(pa[i] + 4);
                pa[i] += 32;
                pb[i] += 32;
            }
        }
        short8 af[4], bfr[4];
#pragma unroll
        for (int f = 0; f < 4; ++f) {
            af[f]  = *(const short8*)&As[cur][aoff[f]];
            bfr[f] = *(const short8*)&Bs[cur][boff[f]];
        }
        __builtin_amdgcn_s_setprio(1);
#pragma unroll
        for (int fm = 0; fm < 4; ++fm)
#pragma unroll
            for (int fn = 0; fn < 4; ++fn)
                acc[fm][fn] = __builtin_amdgcn_mfma_f32_16x16x32_bf16(af[fm], bfr[fn], acc[fm][fn], 0, 0, 0);
        __builtin_amdgcn_s_setprio(0);
        if (more) {
#pragma unroll
            for (int i = 0; i < 2; ++i) {
                uint4 r;
                r.x = cvtpk_bf16(va[i].x, va[i].y);
                r.y = cvtpk_bf16(va[i].z, va[i].w);
                r.z = cvtpk_bf16(vb[i].x, vb[i].y);
                r.w = cvtpk_bf16(vb[i].z, vb[i].w);
                *(uint4*)&As[cur ^ 1][ldsoff[i]] = r;
            }
        }
        __syncthreads();
        cur ^= 1;
    }

    // epilogue: bias, scale, bf16 store
#pragma unroll
    for (int fn = 0; fn < 4; ++fn) {
        int col = n0 + wn * 64 + fn * 16 + lr;
        float bv = bias[col];
#pragma unroll
        for (int fm = 0; fm < 4; ++fm)
#pragma unroll
            for (int j = 0; j < 4; ++j) {
                int row = m0 + wm * 64 + fm * 16 + lg * 4 + j;
                Out[(size_t)row * 1024 + col] = f2bf((acc[fm][fn][j] + bv) * scale);
            }
    }
}

// ---------------------------------------------------------------------------
// Kernel 3: flash attention, swapped-QK^T, exp2-domain, fully deferred softmax.
//   Steady state has ZERO cross-lane ops: lane-local max trigger test, per-lane
//   partial l (reduced once in epilogue). Rescale path (full per-row shfl
//   reduce + o-rescale) fires ~once per block (first tile).
// ---------------------------------------------------------------------------
__global__ __launch_bounds__(512, 4) void attn_kernel(const u16* __restrict__ Qb,
                                                      const u16* __restrict__ Kb,
                                                      const u16* __restrict__ Vt,
                                                      float* __restrict__ AO) {
    __shared__ __align__(16) u16 Kbuf[2][64 * 128];   // 32 KB
    __shared__ __align__(16) u16 Vbuf[2][128 * 64];   // 32 KB
    __shared__ __align__(16) u16 Pl[8][16 * 64];      // 16 KB

    // XCD swizzle: 512 blocks, 8 XCDs -> 64 consecutive swz per XCD = 8 full heads
    int bid = blockIdx.x;
    int swz = (bid & 7) * 64 + (bid >> 3);
    int bh  = swz >> 3;
    int qt  = swz & 7;
    int b = bh >> 3, h = bh & 7;
    int q0 = qt * 128;

    int t = threadIdx.x, lane = t & 63, w = t >> 6;
    int lr = lane & 15, lg = lane >> 4;

    // Q fragments (B-operand: col = q-row = lr), pre-scaled by log2e/sqrt(DH)
    short8 qf[4];
    {
        size_t qbase = (size_t)(b * SEQ + q0 + w * 16 + lr) * 1024 + h * DHEAD;
#pragma unroll
        for (int kk = 0; kk < 4; ++kk)
            qf[kk] = *(const short8*)&Qb[qbase + kk * 32 + lg * 8];
    }

    float m_i = -1e30f, l_loc = 0.f;   // l_loc: per-lane partial denominator
    f32x4 o[8] = {};
    u16* Pw = &Pl[w][0];
    const int pwrow = lr * 64;
    const int lx = lr & 7;

#define STAGE(nb, kk0)                                                                   \
    {                                                                                    \
        _Pragma("unroll")                                                                \
        for (int i = 0; i < 2; ++i) {                                                    \
            int g = (w * 2 + i) * 64 + lane;                                             \
            int row = g >> 4, cp = g & 15;                                               \
            int c = cp ^ (row & 7);                                                      \
            const u16* src = Kb + ((size_t)(b * SEQ + (kk0) + row) * 1024 + h * 128 + c * 8); \
            GLL16(src, &Kbuf[nb][(w * 2 + i) * 512]);                                    \
        }                                                                                \
        _Pragma("unroll")                                                                \
        for (int i = 0; i < 2; ++i) {                                                    \
            int g = (w * 2 + i) * 64 + lane;                                             \
            int d = g >> 3, cp = g & 7;                                                  \
            int c = cp ^ (d & 7);                                                        \
            const u16* src = Vt + ((size_t)(bh * 128 + d) * 1024 + (kk0) + c * 8);       \
            GLL16(src, &Vbuf[nb][(w * 2 + i) * 512]);                                    \
        }                                                                                \
    }

    STAGE(0, 0);
    __syncthreads();

    int cur = 0;
    for (int k0 = 0; k0 < SEQ; k0 += 64) {
        if (k0 + 64 < SEQ) STAGE(cur ^ 1, k0 + 64);

        // ---- S^T = K Q : s[fn][j] = S[q=lr][key = fn*16 + lg*4 + j] (log2 dom.)
        const u16* Kc = &Kbuf[cur][0];
        f32x4 s[4] = {};
        __builtin_amdgcn_s_setprio(1);
#pragma unroll
        for (int fn = 0; fn < 4; ++fn) {
            int krow = (fn * 16 + lr) * 128;
#pragma unroll
            for (int kk = 0; kk < 4; ++kk) {
                short8 kf = *(const short8*)&Kc[krow + (((kk * 4 + lg) ^ lx) << 3)];
                s[fn] = __builtin_amdgcn_mfma_f32_16x16x32_bf16(kf, qf[kk], s[fn], 0, 0, 0);
            }
        }
        __builtin_amdgcn_s_setprio(0);

        // ---- deferred softmax: lane-local max test, no cross-lane steady-state
        float pm0 = fmaxf(fmaxf(s[0][0], s[0][1]), fmaxf(s[0][2], s[0][3]));
        float pm1 = fmaxf(fmaxf(s[1][0], s[1][1]), fmaxf(s[1][2], s[1][3]));
        float pm2 = fmaxf(fmaxf(s[2][0], s[2][1]), fmaxf(s[2][2], s[2][3]));
        float pm3 = fmaxf(fmaxf(s[3][0], s[3][1]), fmaxf(s[3][2], s[3][3]));
        float pmax = fmaxf(fmaxf(pm0, pm1), fmaxf(pm2, pm3));

        if (__any(pmax > m_i + 11.5416f)) {   // ~8 nats in log2 units
            float rm = pmax;                  // full per-row reduce (rare)
            rm = fmaxf(rm, __shfl_xor(rm, 16));
            rm = fmaxf(rm, __shfl_xor(rm, 32));
            float mnew = fmaxf(m_i, rm);
            float alpha = exp2_fast(m_i - mnew);
            m_i = mnew;
            l_loc *= alpha;
#pragma unroll
            for (int db = 0; db < 8; ++db) o[db] *= alpha;
        }

        float p[4][4];
        float ls0 = 0.f, ls1 = 0.f, ls2 = 0.f, ls3 = 0.f;
#pragma unroll
        for (int j = 0; j < 4; ++j) {
            p[0][j] = exp2_fast(s[0][j] - m_i); ls0 += p[0][j];
            p[1][j] = exp2_fast(s[1][j] - m_i); ls1 += p[1][j];
            p[2][j] = exp2_fast(s[2][j] - m_i); ls2 += p[2][j];
            p[3][j] = exp2_fast(s[3][j] - m_i); ls3 += p[3][j];
        }
        l_loc += (ls0 + ls1) + (ls2 + ls3);

        // ---- P^T -> LDS: Pw[q=lr][key], packed b64 writes via v_cvt_pk ----
#pragma unroll
        for (int fn = 0; fn < 4; ++fn) {
            uint2 pk;
            pk.x = cvtpk_bf16(p[fn][0], p[fn][1]);
            pk.y = cvtpk_bf16(p[fn][2], p[fn][3]);
            int idx = pwrow + (((fn * 2 + (lg >> 1)) ^ lx) << 3) + ((lg & 1) << 2);
            *(uint2*)&Pw[idx] = pk;
        }

        // ---- O^T += V^T P^T ----
        const u16* Vc = &Vbuf[cur][0];
        short8 pf0 = *(const short8*)&Pw[pwrow + ((lg ^ lx) << 3)];
        short8 pf1 = *(const short8*)&Pw[pwrow + (((4 + lg) ^ lx) << 3)];
        __builtin_amdgcn_s_setprio(1);
#pragma unroll
        for (int db = 0; db < 8; ++db) {
            int vr = (db * 16 + lr) * 64;
            short8 v0 = *(const short8*)&Vc[vr + ((lg ^ lx) << 3)];
            short8 v1 = *(const short8*)&Vc[vr + (((4 + lg) ^ lx) << 3)];
            o[db] = __builtin_amdgcn_mfma_f32_16x16x32_bf16(v0, pf0, o[db], 0, 0, 0);
            o[db] = __builtin_amdgcn_mfma_f32_16x16x32_bf16(v1, pf1, o[db], 0, 0, 0);
        }
        __builtin_amdgcn_s_setprio(0);

        __syncthreads();   // drains vmcnt(0): next tile resident; LDS reads done
        cur ^= 1;
    }

    // epilogue: reduce denominator across the 4 lanes of each q-row, store
    float lt = l_loc;
    lt += __shfl_xor(lt, 16);
    lt += __shfl_xor(lt, 32);
    float inv = 1.f / lt;
    size_t obase = (size_t)(b * SEQ + q0 + w * 16 + lr) * 1024 + h * DHEAD + lg * 4;
#pragma unroll
    for (int db = 0; db < 8; ++db) {
        float4 ov;
        ov.x = o[db][0] * inv;
        ov.y = o[db][1] * inv;
        ov.z = o[db][2] * inv;
        ov.w = o[db][3] * inv;
        *(float4*)&AO[obase + db * 16] = ov;
    }
#undef STAGE
}

// ---------------------------------------------------------------------------
// Kernel 4: residual blend + LayerNorm, in place on d_out.
// ---------------------------------------------------------------------------
__global__ __launch_bounds__(256) void ln_kernel(float* __restrict__ AO,
                                                 const float* __restrict__ qin,
                                                 const float* __restrict__ gamma,
                                                 const float* __restrict__ beta,
                                                 float* __restrict__ out) {
    __shared__ float red[8];
    int row = blockIdx.x;
    int t = threadIdx.x;
    size_t base = (size_t)row * 1024 + t * 4;

    float4 a = *(const float4*)&AO[base];
    float4 qq = *(const float4*)&qin[base];
    float x0 = a.x * 0.1f + qq.x * 0.9f;
    float x1 = a.y * 0.1f + qq.y * 0.9f;
    float x2 = a.z * 0.1f + qq.z * 0.9f;
    float x3 = a.w * 0.1f + qq.w * 0.9f;

    float s  = x0 + x1 + x2 + x3;
    float s2 = x0 * x0 + x1 * x1 + x2 * x2 + x3 * x3;
    for (int d = 1; d < 64; d <<= 1) {
        s  += __shfl_xor(s, d);
        s2 += __shfl_xor(s2, d);
    }
    int w = t >> 6, lane = t & 63;
    if (lane == 0) { red[w] = s; red[4 + w] = s2; }
    __syncthreads();
    s  = red[0] + red[1] + red[2] + red[3];
    s2 = red[4] + red[5] + red[6] + red[7];

    float mu   = s * (1.f / 1024.f);
    float var  = s2 * (1.f / 1024.f) - mu * mu;
    float rstd = rsqrtf(var + 1e-5f);

    float4 g  = *(const float4*)&gamma[t * 4];
    float4 be = *(const float4*)&beta[t * 4];
    float4 o;
    o.x = (x0 - mu) * rstd * g.x + be.x;
    o.y = (x1 - mu) * rstd * g.y + be.y;
    o.z = (x2 - mu) * rstd * g.z + be.z;
    o.w = (x3 - mu) * rstd * g.w + be.w;
    *(float4*)&out[base] = o;
}

// ---------------------------------------------------------------------------
extern "C" void kernel_launch(void* const* d_in, const int* in_sizes, int n_in,
                              void* d_out, int out_size, void* d_ws, size_t ws_size,
                              hipStream_t stream) {
    const float* q     = (const float*)d_in[0];
    const float* k     = (const float*)d_in[1];
    const float* Wq    = (const float*)d_in[2];
    const float* bq    = (const float*)d_in[3];
    const float* Wk    = (const float*)d_in[4];
    const float* bk    = (const float*)d_in[5];
    const float* gamma = (const float*)d_in[6];
    const float* beta  = (const float*)d_in[7];
    float* out = (float*)d_out;

    char* ws = (char*)d_ws;
    u16* WqT = (u16*)ws;                             // 2 MB
    u16* WkT = (u16*)(ws + (size_t)(2  << 20));      // 2 MB
    u16* Qb  = (u16*)(ws + (size_t)(4  << 20));      // 16 MB
    u16* Kb  = (u16*)(ws + (size_t)(20 << 20));      // 16 MB
    u16* Vt  = (u16*)(ws + (size_t)(36 << 20));      // 16 MB  (total 52 MB)

    // 1) W transposes + k -> Vt
    transpose_conv<<<dim3(32, 32, 2 + BATCH), dim3(32, 8), 0, stream>>>(Wq, Wk, k, WqT, WkT, Vt);

    // 2) both projections in one launch, A read as fp32 directly
    gemm_dual<<<1024, 256, 0, stream>>>(q, k, WqT, WkT, bq, bk, Qb, Kb);

    // 3) attention -> d_out (fp32, pre-LN)
    attn_kernel<<<512, 512, 0, stream>>>(Qb, Kb, Vt, out);

    // 4) residual + layernorm in place
    ln_kernel<<<8192, 256, 0, stream>>>(out, q, gamma, beta, out);
}